// Round 18
// baseline (626.552 us; speedup 1.0000x reference)
//
#include <hip/hip_runtime.h>

typedef float floatx4 __attribute__((ext_vector_type(4)));
typedef short shortx8 __attribute__((ext_vector_type(8)));

struct P5 { const void* p[5]; };

__device__ __forceinline__ float bf16_to_f(unsigned short u) {
    union { unsigned int i; float f; } v;
    v.i = ((unsigned int)u) << 16;
    return v.f;
}
__device__ __forceinline__ unsigned short f_to_bf16(float f) {
    union { float f; unsigned int i; } v;
    v.f = f;
    unsigned int lsb = (v.i >> 16) & 1u;
    unsigned int r = v.i + 0x7fffu + lsb;
    return (unsigned short)(r >> 16);
}

#define E_TOT 2720000
#define N_TOT 180000
#define CAP 96        // max degree bound: worst-type mean 32, P(deg>=96) ~ 1e-20

// two-pass build (R13-verified): k_binA bins edges into 704 buckets of 256
// slots (w>>8) with per-block LDS histograms + ONE global atomic per
// (block,bucket) reservation; k_placeB places via LDS cursors, coalesced out.
#define EPB 2048           // edges per k_binA block
#define NBA 1329           // ceil(E_TOT / EPB)
#define NBKT2 704          // ceil(N_TOT / 256)
#define BCAP2 9216         // worst bucket (drug region): mean 8192, sigma ~90 -> +11 sigma
#define GCNT_STRIDE 16     // one counter per 64B line
#define NB_MERGED (NBA + 11024)  // 1329 bin + 10000 cast + 512 bw0 + 512 bw1

// ---------------- zero (bucket counters) ----------------
__global__ __launch_bounds__(256) void k_zero(int* __restrict__ p, int n) {
    int i = blockIdx.x * 256 + threadIdx.x;
    if (i < n) p[i] = 0;
}

// ---------------- build_w body (fp32 in, bf16 out) ----------------
// Wt layouts (bf16, [128 n x K k] row-major):
//  gene K=512: [Wl(e0)|Wl(e3)|Wl(e4)|Wr(e0)+Wr(e3)+Wr(e4)]
//  drug K=256: [Wl(e1)|Wr(e1)]   dis K=256: [Wl(e2)|Wr(e2)]
__device__ void build_w_body(const float* Wl, const float* Wr, const float* bl,
                             int l, int t,
                             unsigned short* Wg, unsigned short* Wd,
                             unsigned short* Ws, float* bg, float* bd, float* bs) {
    if (t < 128 * 512) {
        int n = t >> 9;
        int kg = t & 511;
        int b = kg >> 7, k = kg & 127;
        float v;
        if (b == 0)
            v = Wl[(((size_t)l * 5 + 0) * 128 + n) * 128 + k];
        else if (b == 1)
            v = Wl[(((size_t)l * 5 + 3) * 128 + n) * 128 + k];
        else if (b == 2)
            v = Wl[(((size_t)l * 5 + 4) * 128 + n) * 128 + k];
        else
            v = Wr[(((size_t)l * 5 + 0) * 128 + n) * 128 + k] +
                Wr[(((size_t)l * 5 + 3) * 128 + n) * 128 + k] +
                Wr[(((size_t)l * 5 + 4) * 128 + n) * 128 + k];
        Wg[n * 512 + kg] = f_to_bf16(v);
    } else if (t < 131072) {
        int t2 = t - 65536;
        int which = (t2 >= 32768) ? 1 : 0;  // 0=drug(e1), 1=disease(e2)
        int t3 = which ? t2 - 32768 : t2;
        int n = t3 >> 8;
        int kg = t3 & 255;
        int b = kg >> 7, k = kg & 127;
        int ei = which ? 2 : 1;
        float v = (b == 0) ? Wl[(((size_t)l * 5 + ei) * 128 + n) * 128 + k]
                           : Wr[(((size_t)l * 5 + ei) * 128 + n) * 128 + k];
        (which ? Ws : Wd)[n * 256 + kg] = f_to_bf16(v);
    }
    if (t < 128) {
        int n = t;
        bg[n] = bl[((size_t)l * 5 + 0) * 128 + n] +
                bl[((size_t)l * 5 + 3) * 128 + n] +
                bl[((size_t)l * 5 + 4) * 128 + n];
        bd[n] = bl[((size_t)l * 5 + 1) * 128 + n];
        bs[n] = bl[((size_t)l * 5 + 2) * 128 + n];
    }
}

// ---------------- pass A: LDS-histogram binning + block reservation ----------
__global__ __launch_bounds__(256) void k_binA(P5 src, P5 dst,
                                              int* __restrict__ gCnt,
                                              unsigned int* __restrict__ bktBuf,
                                              const float* __restrict__ drug,
                                              const float* __restrict__ dis,
                                              const float* __restrict__ gene,
                                              unsigned short* __restrict__ xb,
                                              const float* __restrict__ Wl,
                                              const float* __restrict__ Wr,
                                              const float* __restrict__ bl,
                                              unsigned short* __restrict__ Wg0,
                                              unsigned short* __restrict__ Wd0,
                                              unsigned short* __restrict__ Ws0,
                                              float* __restrict__ bg0,
                                              float* __restrict__ bd0,
                                              float* __restrict__ bs0,
                                              unsigned short* __restrict__ Wg1,
                                              unsigned short* __restrict__ Wd1,
                                              unsigned short* __restrict__ Ws1,
                                              float* __restrict__ bg1,
                                              float* __restrict__ bd1,
                                              float* __restrict__ bs1) {
    __shared__ unsigned int recs[EPB];      // 8 KB
    __shared__ unsigned short bkts[EPB];    // 4 KB
    __shared__ int hist[NBKT2];             // 2.75 KB
    __shared__ int gbase[NBKT2];
    __shared__ int cursor[NBKT2];
    const int b = blockIdx.x;
    const int tid = threadIdx.x;
    if (b < NBA) {
        for (int t = tid; t < NBKT2; t += 256) hist[t] = 0;
        __syncthreads();
        const int ebase[5] = {0, 640000, 1280000, 1600000, 1920000};
        const int noff[5]  = {0, 50000, 70000, 80000, 130000};
        for (int r = 0; r < 8; ++r) {
            int il = r * 256 + tid;
            int g = b * EPB + il;
            if (g < E_TOT) {
                int t = (g < 640000) ? 0 : (g < 1280000) ? 1 : (g < 1600000) ? 2
                        : (g < 1920000) ? 3 : 4;
                int e = g - ebase[t];
                int s = ((const int*)src.p[t])[e];
                int d = ((const int*)dst.p[t])[e];
                int w = noff[t] + d;
                int bk = w >> 8;
                recs[il] = ((unsigned int)(w & 255) << 16) | (unsigned int)s;  // src < 65536
                bkts[il] = (unsigned short)bk;
                atomicAdd(&hist[bk], 1);
            }
        }
        __syncthreads();
        for (int t = tid; t < NBKT2; t += 256) {
            int h = hist[t];
            gbase[t] = h ? atomicAdd(&gCnt[t * GCNT_STRIDE], h) : 0;
            cursor[t] = 0;
        }
        __syncthreads();
        for (int r = 0; r < 8; ++r) {
            int il = r * 256 + tid;
            int g = b * EPB + il;
            if (g < E_TOT) {
                unsigned int rec = recs[il];
                int bk = bkts[il];
                int rank = atomicAdd(&cursor[bk], 1);
                int idx = gbase[bk] + rank;
                if (idx < BCAP2)
                    bktBuf[(size_t)bk * BCAP2 + idx] = rec;
            }
        }
        return;
    }
    int pb = b - NBA;
    if (pb < 10000) {
        int i = (pb * 256 + threadIdx.x) * 4;
        if (i >= 10240000) return;
        const float* sp;
        int off;
        if (i < 2560000) { sp = drug; off = i; }
        else if (i < 3840000) { sp = dis; off = i - 2560000; }
        else { sp = gene; off = i - 3840000; }
        floatx4 v = *(const floatx4*)(sp + off);
        ushort4 r;
        r.x = f_to_bf16(v[0]);
        r.y = f_to_bf16(v[1]);
        r.z = f_to_bf16(v[2]);
        r.w = f_to_bf16(v[3]);
        *(ushort4*)(xb + i) = r;
    } else if (pb < 10512) {
        build_w_body(Wl, Wr, bl, 0, (pb - 10000) * 256 + threadIdx.x,
                     Wg0, Wd0, Ws0, bg0, bd0, bs0);
    } else {
        build_w_body(Wl, Wr, bl, 1, (pb - 10512) * 256 + threadIdx.x,
                     Wg1, Wd1, Ws1, bg1, bd1, bs1);
    }
}

// ---------------- pass B: LDS-staged placement, coalesced esF write ----------
__global__ __launch_bounds__(256) void k_placeB(const int* __restrict__ gCnt,
                                                const unsigned int* __restrict__ bktBuf,
                                                int* __restrict__ cnt,
                                                unsigned short* __restrict__ esF) {
    __shared__ __align__(16) unsigned short sE[256 * CAP];  // 48 KB
    __shared__ int scnt[256];
    const int b = blockIdx.x;
    const int tid = threadIdx.x;
    scnt[tid] = 0;
    __syncthreads();
    int n = gCnt[b * GCNT_STRIDE];
    if (n > BCAP2) n = BCAP2;
    const unsigned int* bp = bktBuf + (size_t)b * BCAP2;
    for (int i = tid; i < n; i += 256) {
        unsigned int rec = bp[i];
        int local = rec >> 16;
        int pos = atomicAdd(&scnt[local], 1);
        if (pos < CAP)
            sE[local * CAP + pos] = (unsigned short)(rec & 0xffffu);
    }
    __syncthreads();
    int w0 = b * 256;
    int nslot = N_TOT - w0;
    if (nslot > 256) nslot = 256;
    int nvec = nslot * 12;
    const uint4* s4 = (const uint4*)sE;
    uint4* g4 = (uint4*)(esF + (size_t)w0 * CAP);
    for (int i = tid; i < nvec; i += 256) g4[i] = s4[i];
    if (tid < nslot) cnt[w0 + tid] = scnt[tid];
}

// ---------------- fused gather+mean+GEMM (3 jobs per layer) ------------------
// out[M,128] = relu( ( [mean_0|..|mean_{nacc-1}|x] @ Wt^T + bias ) * invk ).
// Each K-chunk s < nacc builds its A-tile (64 rows x 128) in LDS directly from
// neighbor gathers (agg fused away): per wave, 4 lane-groups own one row each
// (16 lanes x 8 cols -> no shfl reduce), two rows per group as independent
// chains for 2-stream ILP. s == nacc stages the x rows. MFMA reads A and B
// from LDS (row pad 136 ushorts = 272B -> 2 lanes/bank, conflict-free m136).
// Removes mean buffer (45MB write + 90MB read L2 traffic/layer) and overlaps
// MFMA+W-staging under the gather service bound (agg was 91us, gemm ~40us
// serialized; R16 showed agg ILP tuning exhausted at ~3TB/s service).
struct FJob {
    const unsigned short *g0, *g1, *g2;  // gather source tables per mean chunk
    int sb0, sb1, sb2;                   // slot bases (w = sb + row)
    const unsigned short* x;
    const unsigned short* Wt;
    const float* bias;
    float invk;
    void* out;
    int M, nacc;
};
struct FJobs { FJob j[3]; };

#define BPAD 136

template <bool OUTBF>
__global__ __launch_bounds__(256) void k_fgemm3(FJobs jobs,
                                                const int* __restrict__ cnt,
                                                const unsigned short* __restrict__ esF) {
    __shared__ __align__(16) unsigned short sB[128 * BPAD];  // 34.8 KB
    __shared__ __align__(16) unsigned short sA[64 * BPAD];   // 17.4 KB
    const int b = blockIdx.x;
    int ji, bloc;
    if (b < 782) { ji = 0; bloc = b; }
    else if (b < 1095) { ji = 1; bloc = b - 782; }
    else { ji = 2; bloc = b - 1095; }
    const FJob& J = jobs.j[ji];
    const int K = (J.nacc + 1) << 7;
    const int tid = threadIdx.x;
    const int lane = tid & 63;
    const int wave = tid >> 6;
    const int quad = lane >> 4;
    const int l16 = lane & 15;
    const int grp = lane >> 4;       // row-group within wave (A build)
    const int sub = lane & 15;       // 16 lanes cover 128 cols
    const int c0 = sub << 3;
    const int blk_base = bloc * 64;
    const int wrow_base = blk_base + wave * 16;

    // W staging coords: thread t covers row t>>1, half t&1
    const int srow = tid >> 1;
    const int shalf = tid & 1;
    unsigned short* sdst = sB + srow * BPAD + shalf * 64;

    floatx4 acc[8];
#pragma unroll
    for (int i = 0; i < 8; i++) acc[i] = floatx4{0.f, 0.f, 0.f, 0.f};

    for (int s = 0; s <= J.nacc; s++) {
        // ---- issue W chunk staging (coalesced, overlaps with A build) ----
        {
            const unsigned short* wsrc =
                J.Wt + (size_t)srow * K + (s << 7) + shalf * 64;
#pragma unroll
            for (int i = 0; i < 8; i++) {
                *(shortx8*)(sdst + i * 8) = *(const shortx8*)(wsrc + i * 8);
            }
        }
        // ---- build A chunk ----
        if (s < J.nacc) {
            const unsigned short* gt = (s == 0) ? J.g0 : (s == 1) ? J.g1 : J.g2;
            int sb = (s == 0) ? J.sb0 : (s == 1) ? J.sb1 : J.sb2;
            const unsigned short* xp = gt + c0;
#pragma unroll
            for (int half = 0; half < 2; ++half) {
                int arowA = half * 4 + grp;       // 0..7
                int arowB = arowA + 8;            // 8..15
                int rowA = wrow_base + arowA;
                int rowB = wrow_base + arowB;
                if (rowA > J.M - 1) rowA = J.M - 1;
                if (rowB > J.M - 1) rowB = J.M - 1;
                int wA = sb + rowA, wB = sb + rowB;
                int na = cnt[wA]; if (na > CAP) na = CAP; if (na < 0) na = 0;
                int nb_ = cnt[wB]; if (nb_ > CAP) nb_ = CAP; if (nb_ < 0) nb_ = 0;
                const unsigned short* epA = esF + (size_t)wA * CAP;
                const unsigned short* epB = esF + (size_t)wB * CAP;
                int nm = (na > nb_) ? na : nb_;
                nm = max(nm, __shfl_xor(nm, 16));
                nm = max(nm, __shfl_xor(nm, 32));
                float a0 = 0.f, a1 = 0.f, a2 = 0.f, a3 = 0.f;
                float a4 = 0.f, a5 = 0.f, a6 = 0.f, a7 = 0.f;
                float b0 = 0.f, b1 = 0.f, b2 = 0.f, b3 = 0.f;
                float b4 = 0.f, b5 = 0.f, b6 = 0.f, b7 = 0.f;
                for (int j = 0; j < nm; ++j) {
                    uint4 pa, pb;
                    bool va = j < na, vb = j < nb_;
                    if (va) pa = *(const uint4*)(xp + ((size_t)epA[j] << 7));
                    if (vb) pb = *(const uint4*)(xp + ((size_t)epB[j] << 7));
                    if (va) {
                        a0 += bf16_to_f((unsigned short)(pa.x & 0xffffu));
                        a1 += bf16_to_f((unsigned short)(pa.x >> 16));
                        a2 += bf16_to_f((unsigned short)(pa.y & 0xffffu));
                        a3 += bf16_to_f((unsigned short)(pa.y >> 16));
                        a4 += bf16_to_f((unsigned short)(pa.z & 0xffffu));
                        a5 += bf16_to_f((unsigned short)(pa.z >> 16));
                        a6 += bf16_to_f((unsigned short)(pa.w & 0xffffu));
                        a7 += bf16_to_f((unsigned short)(pa.w >> 16));
                    }
                    if (vb) {
                        b0 += bf16_to_f((unsigned short)(pb.x & 0xffffu));
                        b1 += bf16_to_f((unsigned short)(pb.x >> 16));
                        b2 += bf16_to_f((unsigned short)(pb.y & 0xffffu));
                        b3 += bf16_to_f((unsigned short)(pb.y >> 16));
                        b4 += bf16_to_f((unsigned short)(pb.z & 0xffffu));
                        b5 += bf16_to_f((unsigned short)(pb.z >> 16));
                        b6 += bf16_to_f((unsigned short)(pb.w & 0xffffu));
                        b7 += bf16_to_f((unsigned short)(pb.w >> 16));
                    }
                }
                float icA = 1.0f / (float)((na > 1) ? na : 1);
                float icB = 1.0f / (float)((nb_ > 1) ? nb_ : 1);
                uint4 oa, ob;
                oa.x = (unsigned int)f_to_bf16(a0 * icA) | ((unsigned int)f_to_bf16(a1 * icA) << 16);
                oa.y = (unsigned int)f_to_bf16(a2 * icA) | ((unsigned int)f_to_bf16(a3 * icA) << 16);
                oa.z = (unsigned int)f_to_bf16(a4 * icA) | ((unsigned int)f_to_bf16(a5 * icA) << 16);
                oa.w = (unsigned int)f_to_bf16(a6 * icA) | ((unsigned int)f_to_bf16(a7 * icA) << 16);
                ob.x = (unsigned int)f_to_bf16(b0 * icB) | ((unsigned int)f_to_bf16(b1 * icB) << 16);
                ob.y = (unsigned int)f_to_bf16(b2 * icB) | ((unsigned int)f_to_bf16(b3 * icB) << 16);
                ob.z = (unsigned int)f_to_bf16(b4 * icB) | ((unsigned int)f_to_bf16(b5 * icB) << 16);
                ob.w = (unsigned int)f_to_bf16(b6 * icB) | ((unsigned int)f_to_bf16(b7 * icB) << 16);
                *(uint4*)(sA + (wave * 16 + arowA) * BPAD + c0) = oa;
                *(uint4*)(sA + (wave * 16 + arowB) * BPAD + c0) = ob;
            }
        } else {
            // A = x rows: 64 rows x 256B = 16KB, 256 thr x 16B x 4 iters
#pragma unroll
            for (int i = 0; i < 4; ++i) {
                int idx = i * 256 + tid;
                int arow = idx >> 4;
                int o16 = (idx & 15) << 3;   // ushort offset
                int row = blk_base + arow;
                if (row > J.M - 1) row = J.M - 1;
                *(uint4*)(sA + arow * BPAD + o16) =
                    *(const uint4*)(J.x + ((size_t)row << 7) + o16);
            }
        }
        __syncthreads();
        // ---- MFMA: A and B both from LDS ----
#pragma unroll
        for (int kq = 0; kq < 4; kq++) {
            const int ko = (kq << 5) + (quad << 3);
            shortx8 afrag = *(const shortx8*)(sA + (wave * 16 + l16) * BPAD + ko);
#pragma unroll
            for (int nt = 0; nt < 8; nt++) {
                shortx8 bfrag =
                    *(const shortx8*)(sB + ((nt << 4) + l16) * BPAD + ko);
                acc[nt] = __builtin_amdgcn_mfma_f32_16x16x32_bf16(afrag, bfrag, acc[nt], 0, 0, 0);
            }
        }
        __syncthreads();
    }

    // epilogue: D mapping col=lane&15, row=quad*4+reg
#pragma unroll
    for (int nt = 0; nt < 8; nt++) {
        const int col = (nt << 4) + l16;
        const float bv = J.bias[col];
#pragma unroll
        for (int r = 0; r < 4; r++) {
            const int orow = wrow_base + (quad << 2) + r;
            if (orow < J.M) {
                float v = fmaxf((acc[nt][r] + bv) * J.invk, 0.f);
                if (OUTBF)
                    ((unsigned short*)J.out)[((size_t)orow << 7) + col] = f_to_bf16(v);
                else
                    ((float*)J.out)[((size_t)orow << 7) + col] = v;
            }
        }
    }
}

extern "C" void kernel_launch(void* const* d_in, const int* in_sizes, int n_in,
                              void* d_out, int out_size, void* d_ws, size_t ws_size,
                              hipStream_t stream) {
    const float* emb_drug = (const float*)d_in[0];
    const float* emb_dis  = (const float*)d_in[1];
    const float* emb_gene = (const float*)d_in[2];
    const float* Wl = (const float*)d_in[3];
    const float* Wr = (const float*)d_in[4];
    const float* bl = (const float*)d_in[5];
    P5 srcs = {{d_in[6], d_in[8], d_in[10], d_in[12], d_in[14]}};
    P5 dsts = {{d_in[7], d_in[9], d_in[11], d_in[13], d_in[15]}};

    char* base = (char*)d_ws;
    size_t off = 0;
    auto alloc = [&](size_t bytes) -> void* {
        void* r = base + off;
        off = (off + bytes + 255) & ~(size_t)255;
        return r;
    };
    int* cnt = (int*)alloc((size_t)N_TOT * 4);
    unsigned short* esF = (unsigned short*)alloc((size_t)N_TOT * CAP * 2);
    unsigned short* xb = (unsigned short*)alloc(80000ull * 128 * 2);
    unsigned short* xb_drug = xb;
    unsigned short* xb_dis  = xb + 20000ull * 128;
    unsigned short* xb_gene = xb + 30000ull * 128;
    unsigned short* x1_drug = (unsigned short*)alloc(20000ull * 128 * 2);
    unsigned short* x1_dis  = (unsigned short*)alloc(10000ull * 128 * 2);
    unsigned short* x1_gene = (unsigned short*)alloc(50000ull * 128 * 2);
    unsigned short* Wg0 = (unsigned short*)alloc(128ull * 512 * 2);
    unsigned short* Wd0 = (unsigned short*)alloc(128ull * 256 * 2);
    unsigned short* Ws0 = (unsigned short*)alloc(128ull * 256 * 2);
    unsigned short* Wg1 = (unsigned short*)alloc(128ull * 512 * 2);
    unsigned short* Wd1 = (unsigned short*)alloc(128ull * 256 * 2);
    unsigned short* Ws1 = (unsigned short*)alloc(128ull * 256 * 2);
    float* bg0 = (float*)alloc(128 * 4);
    float* bd0 = (float*)alloc(128 * 4);
    float* bs0 = (float*)alloc(128 * 4);
    float* bg1 = (float*)alloc(128 * 4);
    float* bd1 = (float*)alloc(128 * 4);
    float* bs1 = (float*)alloc(128 * 4);
    int* gCnt = (int*)alloc((size_t)NBKT2 * GCNT_STRIDE * 4);
    unsigned int* bktBuf = (unsigned int*)alloc((size_t)NBKT2 * BCAP2 * 4);

    // ---- zero bucket counters, bin (+cast+build_w), place into esF ----
    k_zero<<<(NBKT2 * GCNT_STRIDE + 255) / 256, 256, 0, stream>>>(
        gCnt, NBKT2 * GCNT_STRIDE);
    k_binA<<<NB_MERGED, 256, 0, stream>>>(srcs, dsts, gCnt, bktBuf,
                                          emb_drug, emb_dis, emb_gene, xb,
                                          Wl, Wr, bl,
                                          Wg0, Wd0, Ws0, bg0, bd0, bs0,
                                          Wg1, Wd1, Ws1, bg1, bd1, bs1);
    k_placeB<<<NBKT2, 256, 0, stream>>>(gCnt, bktBuf, cnt, esF);

    // slot regions: e0(gene dst)=[0,50000) e1(drug)=[50000,70000)
    // e2(dis)=[70000,80000) e3(gene)=[80000,130000) e4(gene)=[130000,180000)

    // ---- layer 1 (fused gather+mean+gemm) ----
    FJobs f1 = {{
        {xb_drug, xb_dis, xb_gene, 0, 80000, 130000,
         xb_gene, Wg0, bg0, 1.0f / 3.0f, x1_gene, 50000, 3},
        {xb_gene, nullptr, nullptr, 50000, 0, 0,
         xb_drug, Wd0, bd0, 1.0f, x1_drug, 20000, 1},
        {xb_gene, nullptr, nullptr, 70000, 0, 0,
         xb_dis, Ws0, bs0, 1.0f, x1_dis, 10000, 1},
    }};
    k_fgemm3<true><<<1252, 256, 0, stream>>>(f1, cnt, esF);

    // ---- layer 2 ----
    float* outp = (float*)d_out;
    FJobs f2 = {{
        {x1_drug, x1_dis, x1_gene, 0, 80000, 130000,
         x1_gene, Wg1, bg1, 1.0f / 3.0f, outp + 30000ull * 128, 50000, 3},
        {x1_gene, nullptr, nullptr, 50000, 0, 0,
         x1_drug, Wd1, bd1, 1.0f, outp, 20000, 1},
        {x1_gene, nullptr, nullptr, 70000, 0, 0,
         x1_dis, Ws1, bs1, 1.0f, outp + 20000ull * 128, 10000, 1},
    }};
    k_fgemm3<false><<<1252, 256, 0, stream>>>(f2, cnt, esF);
}